// Round 13
// baseline (87.629 us; speedup 1.0000x reference)
//
#include <hip/hip_runtime.h>
#include <math.h>

#define NDEG 12

typedef unsigned short u16;
typedef unsigned int u32;
typedef _Float16 f16;
typedef __attribute__((ext_vector_type(8))) _Float16 f16x8;
typedef __attribute__((ext_vector_type(8))) short bf16x8;
typedef __attribute__((ext_vector_type(4))) float f32x4;

#define MFMA_F16(a, b, c)  __builtin_amdgcn_mfma_f32_16x16x32_f16(a, b, c, 0, 0, 0)
#define MFMA_BF16(a, b, c) __builtin_amdgcn_mfma_f32_16x16x32_bf16(a, b, c, 0, 0, 0)

__device__ __forceinline__ u32 fbits(float x) { return __float_as_uint(x); }
__device__ __forceinline__ float fval(u32 u) { return __uint_as_float(u); }
__device__ __forceinline__ f32x4 zero4() {
  f32x4 z; z[0] = 0.f; z[1] = 0.f; z[2] = 0.f; z[3] = 0.f; return z;
}
__device__ __forceinline__ u16 f16bits(f16 x) { u16 u; __builtin_memcpy(&u, &x, 2); return u; }
__device__ __forceinline__ float f16tof(u16 u) { f16 h; __builtin_memcpy(&h, &u, 2); return (float)h; }

// bf16 hi (trunc) + bf16 lo (RNE remainder) split  [rounds 2-12 known-good]
__device__ __forceinline__ void split2(float x, u32& h, u32& l) {
  u32 u = fbits(x);
  h = u >> 16;
  float lo = x - fval(u & 0xFFFF0000u);
  u32 v = fbits(lo);
  l = (v + 0x7FFFu + ((v >> 16) & 1u)) >> 16;
}
__device__ __forceinline__ void writePair(u32* Hw, u32* Lw, int widx, float v, int lane) {
  float pv = __shfl_xor(v, 1);
  u32 hv, lv, hp, lp;
  split2(v, hv, lv);
  split2(pv, hp, lp);
  const bool even = (lane & 1) == 0;
  u32 word = even ? (hv | (hp << 16)) : (lp | (lv << 16));
  u32* base = even ? Hw : Lw;
  base[widx] = word;
}

struct CovPh { char buf[65536]; };                       // 4 subtiles x [128][64] f16, swizzled
struct ProjPh { u16 Cov[128][136]; u16 Wt[64][136]; };   // 52224 B
struct ChebPh {
  u16 MH[64][72]; u16 ML[64][72];
  u16 TbH[2][64][72]; u16 TbL[2][64][72];
};                                                        // 55296 B
struct RedPh { float red[256][4]; };                      // 4096 B (overlays ChebPh when dead)
union SmemU { CovPh a; ProjPh p; ChebPh c; RedPh r; };
static_assert(sizeof(SmemU) == 65536, "smem");

// 8-wave Gram split [r11/r12-proven, register-dieted]: row-pair (W, 7-W),
// wave 2W+H takes parity-H entries of the flat upper-tri tile list.
template <int W, int H>
__device__ __forceinline__ void gram8(const char* bufb, int fo0, int fo1,
                                      f32x4 (&acc)[5], f32x4& xs, f16x8 ones) {
  constexpr int I2 = 7 - W;
#pragma unroll
  for (int ch = 0; ch < 2; ++ch) {
    const int fo = ch ? fo1 : fo0;
    const f16x8 Fi1 = *(const f16x8*)(bufb + W * 2048 + fo);
    const f16x8 Fi2 = *(const f16x8*)(bufb + I2 * 2048 + fo);
    const f16x8 Fxs = *(const f16x8*)(bufb + (2 * W + H) * 2048 + fo);
#pragma unroll
    for (int k = 0; k < 9; ++k) {
      if ((k & 1) != H) continue;
      const int I = (k <= 7 - W) ? W : I2;
      const int J = (k <= 7 - W) ? (W + k) : (I2 + (k - (8 - W)));
      const f16x8 Fj = *(const f16x8*)(bufb + J * 2048 + fo);
      acc[k >> 1] = MFMA_F16((I == W) ? Fi1 : Fi2, Fj, acc[k >> 1]);
    }
    xs = MFMA_F16(Fxs, ones, xs);
  }
}

__device__ __forceinline__ void covTile(u16* Cov, const f32x4& v, int I, int J,
                                        int l15, int l16, bool mirror) {
#pragma unroll
  for (int r = 0; r < 4; ++r) {
    int row = 16 * I + 4 * l16 + r;
    int col = 16 * J + l15;
    u16 h = f16bits((f16)(v[r] * 1e-3f));
    Cov[row * 136 + col] = h;
    if (mirror) Cov[col * 136 + row] = h;
  }
}

template <int W, int H>
__device__ __forceinline__ void covStore8(u16* Cov, const f32x4 (&acc)[5], int l15, int l16) {
  constexpr int I2 = 7 - W;
#pragma unroll
  for (int k = 0; k < 9; ++k) {
    if ((k & 1) != H) continue;
    const int I = (k <= 7 - W) ? W : I2;
    const int J = (k <= 7 - W) ? (W + k) : (I2 + (k - (8 - W)));
    covTile(Cov, acc[k >> 1], I, J, l15, l16, I != J);
  }
}

__global__ __launch_bounds__(512, 2) void spdnet_fused11_kernel(
    const float* __restrict__ X, const float* __restrict__ W,
    const float* __restrict__ lin_w, const float* __restrict__ lin_b,
    float* __restrict__ out)
{
  __shared__ SmemU sm;
  __shared__ float mwL[64];
  __shared__ float xsL[128];

  const int tid = threadIdx.x;           // 0..511
  const int lane = tid & 63;
  const int wv = tid >> 6;               // 0..7
  const int l15 = lane & 15;
  const int l16 = lane >> 4;             // 0..3
  const int b = blockIdx.x;
  const char* __restrict__ Xbc = (const char*)(X + (size_t)b * 128000u);

  // ================= phase A: Cov = X X^T, f16 MFMA, 1-KB-contiguous loads =========
  // 4 batches of 256 t. Load instr q (0..15): row rq = 16wv+q, lane sweeps the full
  // 256-t span -> each instruction is one 1-KB CONTIGUOUS DRAM run.
  int voff[16];
#pragma unroll
  for (int q = 0; q < 16; ++q)
    voff[q] = (16 * wv + q) * 4000 + lane * 16;          // byte addr of (rq, t=4*lane)

  // staging addr pieces: subtile s = lane>>4, within-row slot = 8*(lane&15),
  // swizzle bits depend only on q because 16wv ≡ 0 (mod 8).
  const int sBase = (lane >> 4) * 16384 + wv * 2048;
  const int w8 = 8 * (lane & 15);
  // GRAM fragment read offsets (per 16-KB subtile; identical to r11/r12)
  const int swz = (l15 & 7) << 4;
  const int fo0 = l15 * 128 + ((16 * l16) ^ swz);
  const int fo1 = l15 * 128 + ((16 * l16 + 64) ^ swz);

  f16x8 ones;
#pragma unroll
  for (int i = 0; i < 8; ++i) ones[i] = (f16)1.0f;

  f32x4 acc[5];
#pragma unroll
  for (int u = 0; u < 5; ++u) acc[u] = zero4();
  f32x4 xs = zero4();

  float4 ldA[16];   // one batch of 16 x 1-KB-run loads (statically indexed)

#define LB(p)                                                     \
  do {                                                            \
    _Pragma("unroll")                                             \
    for (int q = 0; q < 16; ++q)                                  \
      ldA[q] = *(const float4*)(Xbc + voff[q] + (p) * 1024);      \
  } while (0)
#define LB_TAIL()                                                 \
  do {                                                            \
    const bool valid = lane < 58;                                 \
    const int off = valid ? 3072 : (3984 - 16 * lane);            \
    _Pragma("unroll")                                             \
    for (int q = 0; q < 16; ++q) {                                \
      float4 v = *(const float4*)(Xbc + voff[q] + off);           \
      ldA[q] = valid ? v : make_float4(0.f, 0.f, 0.f, 0.f);       \
    }                                                             \
  } while (0)
#define SB()                                                      \
  do {                                                            \
    char* bb_ = sm.a.buf;                                         \
    _Pragma("unroll")                                             \
    for (int q = 0; q < 16; ++q) {                                \
      u32 w0 = (u32)f16bits((f16)ldA[q].x) | ((u32)f16bits((f16)ldA[q].y) << 16); \
      u32 w1 = (u32)f16bits((f16)ldA[q].z) | ((u32)f16bits((f16)ldA[q].w) << 16); \
      uint2 wr; wr.x = w0; wr.y = w1;                             \
      *(uint2*)(bb_ + sBase + q * 128 + (w8 ^ ((q & 7) << 4))) = wr; \
    }                                                             \
  } while (0)

  auto GRAM4 = [&]() {
    const char* b0 = sm.a.buf;
    switch (wv) {
      case 0: { _Pragma("unroll") for (int s = 0; s < 4; ++s) gram8<0,0>(b0 + s * 16384, fo0, fo1, acc, xs, ones); } break;
      case 1: { _Pragma("unroll") for (int s = 0; s < 4; ++s) gram8<0,1>(b0 + s * 16384, fo0, fo1, acc, xs, ones); } break;
      case 2: { _Pragma("unroll") for (int s = 0; s < 4; ++s) gram8<1,0>(b0 + s * 16384, fo0, fo1, acc, xs, ones); } break;
      case 3: { _Pragma("unroll") for (int s = 0; s < 4; ++s) gram8<1,1>(b0 + s * 16384, fo0, fo1, acc, xs, ones); } break;
      case 4: { _Pragma("unroll") for (int s = 0; s < 4; ++s) gram8<2,0>(b0 + s * 16384, fo0, fo1, acc, xs, ones); } break;
      case 5: { _Pragma("unroll") for (int s = 0; s < 4; ++s) gram8<2,1>(b0 + s * 16384, fo0, fo1, acc, xs, ones); } break;
      case 6: { _Pragma("unroll") for (int s = 0; s < 4; ++s) gram8<3,0>(b0 + s * 16384, fo0, fo1, acc, xs, ones); } break;
      default:{ _Pragma("unroll") for (int s = 0; s < 4; ++s) gram8<3,1>(b0 + s * 16384, fo0, fo1, acc, xs, ones); } break;
    }
  };

  // prologue: batch 0 loaded & staged
  LB(0);
  asm volatile("s_waitcnt vmcnt(0)" ::: "memory");
  SB();
  asm volatile("s_waitcnt lgkmcnt(0)" ::: "memory");
  __builtin_amdgcn_s_barrier();

  // batch p resident in LDS; batch p+1 issued BEFORE the long 4-subtile GRAM so
  // its 16 KB/thread-group stays in flight under compute. Pipe only drains at
  // the per-batch vmcnt(0) (4 boundaries total).
  // p = 0
  LB(1);
  GRAM4();
  __builtin_amdgcn_s_barrier();                   // all reads of batch 0 done
  asm volatile("s_waitcnt vmcnt(0)" ::: "memory");
  SB();
  asm volatile("s_waitcnt lgkmcnt(0)" ::: "memory");
  __builtin_amdgcn_s_barrier();
  // p = 1
  LB(2);
  GRAM4();
  __builtin_amdgcn_s_barrier();
  asm volatile("s_waitcnt vmcnt(0)" ::: "memory");
  SB();
  asm volatile("s_waitcnt lgkmcnt(0)" ::: "memory");
  __builtin_amdgcn_s_barrier();
  // p = 2
  LB_TAIL();
  GRAM4();
  __builtin_amdgcn_s_barrier();
  asm volatile("s_waitcnt vmcnt(0)" ::: "memory");
  SB();
  asm volatile("s_waitcnt lgkmcnt(0)" ::: "memory");
  __builtin_amdgcn_s_barrier();
  // p = 3
  GRAM4();
#undef LB
#undef LB_TAIL
#undef SB

  // row sums from ones-MFMA (cols duplicated -> l15==0 lanes)
  if (l15 == 0) {
#pragma unroll
    for (int r = 0; r < 4; ++r) xsL[16 * wv + 4 * l16 + r] = xs[r];
  }
  __syncthreads();   // phase-A LDS reads done -> overlay allowed

  // ================= phase P: materialize Cov (f16, *1e-3) + Wt =================
  {
    u16* CovP = &sm.p.Cov[0][0];
    switch (wv) {
      case 0: covStore8<0,0>(CovP, acc, l15, l16); break;
      case 1: covStore8<0,1>(CovP, acc, l15, l16); break;
      case 2: covStore8<1,0>(CovP, acc, l15, l16); break;
      case 3: covStore8<1,1>(CovP, acc, l15, l16); break;
      case 4: covStore8<2,0>(CovP, acc, l15, l16); break;
      case 5: covStore8<2,1>(CovP, acc, l15, l16); break;
      case 6: covStore8<3,0>(CovP, acc, l15, l16); break;
      default: covStore8<3,1>(CovP, acc, l15, l16); break;
    }
    u16* WtP = &sm.p.Wt[0][0];
    const int c = tid & 127, dh = tid >> 7;               // dh 0..3
    const float4* wp = (const float4*)(W + c * 64 + 16 * dh);
#pragma unroll
    for (int q = 0; q < 4; ++q) {
      float4 v = wp[q];
      int d0 = 16 * dh + 4 * q;
      WtP[(d0    ) * 136 + c] = f16bits((f16)v.x);
      WtP[(d0 + 1) * 136 + c] = f16bits((f16)v.y);
      WtP[(d0 + 2) * 136 + c] = f16bits((f16)v.z);
      WtP[(d0 + 3) * 136 + c] = f16bits((f16)v.w);
    }
  }
  __syncthreads();

  // mw = W^T xsum * 1e-3 (first 64 threads; overlaps P MFMA elsewhere)
  if (tid < 64) {
    float s = 0.f;
    for (int c = 0; c < 128; ++c)
      s = fmaf(f16tof(sm.p.Wt[tid][c]), xsL[c], s);
    mwL[tid] = s * 1.0e-3f;
  }

  // ---- P = Cov * W  (fp16 MFMA; wave wv owns rows 16wv..16wv+16) ----
  const u16* CovP = &sm.p.Cov[0][0];
  const u16* WtP  = &sm.p.Wt[0][0];
  f32x4 pAcc[4];
#pragma unroll
  for (int n = 0; n < 4; ++n) pAcc[n] = zero4();
#pragma unroll
  for (int ch = 0; ch < 4; ++ch) {
    f16x8 aC = *(const f16x8*)&CovP[(16 * wv + l15) * 136 + 8 * l16 + 32 * ch];
#pragma unroll
    for (int n = 0; n < 4; ++n) {
      f16x8 bw = *(const f16x8*)&WtP[(16 * n + l15) * 136 + 8 * l16 + 32 * ch];
      pAcc[n] = MFMA_F16(aC, bw, pAcc[n]);
    }
  }
  __syncthreads();   // Cov reads done -> Pt may overlay

  // ---- Pt[d][c] = P[c][d]  (fp16, overlays Cov) ----
  {
    u16* PtP = (u16*)&sm.p.Cov[0][0];
#pragma unroll
    for (int n = 0; n < 4; ++n)
#pragma unroll
      for (int r = 0; r < 4; ++r) {
        int c = 16 * wv + 4 * l16 + r;
        int d = 16 * n + l15;
        PtP[d * 136 + c] = f16bits((f16)pAcc[n][r]);
      }
  }
  __syncthreads();

  // ---- Y = W^T P  (waves 0..3 own d-rows 16wv..16wv+16) ----
  const u16* PtP = (const u16*)&sm.p.Cov[0][0];
  f32x4 yAcc[4];
#pragma unroll
  for (int n = 0; n < 4; ++n) yAcc[n] = zero4();
  if (wv < 4) {
#pragma unroll
    for (int ch = 0; ch < 4; ++ch) {
      f16x8 aW = *(const f16x8*)&WtP[(16 * wv + l15) * 136 + 8 * l16 + 32 * ch];
#pragma unroll
      for (int n = 0; n < 4; ++n) {
        f16x8 bP = *(const f16x8*)&PtP[(16 * n + l15) * 136 + 8 * l16 + 32 * ch];
        yAcc[n] = MFMA_F16(aW, bP, yAcc[n]);
      }
    }
  }
  __syncthreads();   // Wt/Pt dead -> Chebyshev planes may overlay

  // ================= phase C: M init + Chebyshev matrix-log (bf16 3-term, waves 0-3) ======
  const float CC = 1.125f;
  const float IH = 1.0f / 0.875f;
  const float uu = 0.875f / 1.125f;
  const float rho = (sqrtf(1.0f - uu * uu) - 1.0f) / uu;   // ~ -0.47759
  const float a0c = logf(CC / (1.0f + rho * rho));
  const float a1c = -2.0f * rho;

  f32x4 zz[4], tp[4], tcu[4];
  if (wv < 4) {
    u32* MHw = (u32*)&sm.c.MH[0][0];
    u32* MLw = (u32*)&sm.c.ML[0][0];
#pragma unroll
    for (int n = 0; n < 4; ++n)
#pragma unroll
      for (int r = 0; r < 4; ++r) {
        int i = 16 * wv + 4 * l16 + r, j = 16 * n + l15;
        float y = yAcc[n][r] - mwL[i] * mwL[j];
        float m = (y - ((i == j) ? CC : 0.f)) * IH;
        float e = (i == j) ? 1.f : 0.f;
        tp[n][r] = e;
        tcu[n][r] = m;
        zz[n][r] = a0c * e + a1c * m;
        writePair(MHw, MLw, i * 36 + (j >> 1), m, lane);
      }
  }
  __syncthreads();

  bf16x8 aMh[2], aMl[2];
  if (wv < 4) {
#pragma unroll
    for (int ch = 0; ch < 2; ++ch) {
      aMh[ch] = *(const bf16x8*)&sm.c.MH[16 * wv + l15][8 * l16 + 32 * ch];
      aMl[ch] = *(const bf16x8*)&sm.c.ML[16 * wv + l15][8 * l16 + 32 * ch];
    }
  }

  float rhok = rho;
  for (int k = 2; k <= NDEG; ++k) {
    rhok *= rho;
    const float ak = (-2.0f / (float)k) * rhok;
    if (wv < 4) {
      const u16 (*srcH)[72] = (k == 2) ? sm.c.MH : sm.c.TbH[(k - 1) & 1];
      const u16 (*srcL)[72] = (k == 2) ? sm.c.ML : sm.c.TbL[(k - 1) & 1];
      f32x4 p[4];
#pragma unroll
      for (int n = 0; n < 4; ++n) p[n] = zero4();
#pragma unroll
      for (int ch = 0; ch < 2; ++ch) {
#pragma unroll
        for (int n = 0; n < 4; ++n) {
          bf16x8 bh = *(const bf16x8*)&srcH[16 * n + l15][8 * l16 + 32 * ch];
          bf16x8 bl = *(const bf16x8*)&srcL[16 * n + l15][8 * l16 + 32 * ch];
          p[n] = MFMA_BF16(aMh[ch], bh, p[n]);
          p[n] = MFMA_BF16(aMh[ch], bl, p[n]);
          p[n] = MFMA_BF16(aMl[ch], bh, p[n]);
        }
      }
      u32* dH = (u32*)&sm.c.TbH[k & 1][0][0];
      u32* dL = (u32*)&sm.c.TbL[k & 1][0][0];
#pragma unroll
      for (int n = 0; n < 4; ++n) {
        f32x4 tn;
#pragma unroll
        for (int r = 0; r < 4; ++r) {
          tn[r] = 2.f * p[n][r] - tp[n][r];
          zz[n][r] = fmaf(ak, tn[r], zz[n][r]);
        }
        tp[n] = tcu[n];
        tcu[n] = tn;
        if (k < NDEG) {
#pragma unroll
          for (int r = 0; r < 4; ++r) {
            int row = 16 * wv + 4 * l16 + r, col = 16 * n + l15;
            writePair(dH, dL, row * 36 + (col >> 1), tn[r], lane);
          }
        }
      }
    }
    if (k < NDEG) __syncthreads();
  }
  __syncthreads();   // Cheb LDS dead -> red overlay allowed

  // ================= classifier (waves 0-3 hold zz) =================
  if (wv < 4) {
    float po[4] = {0.f, 0.f, 0.f, 0.f};
#pragma unroll
    for (int n = 0; n < 4; ++n)
#pragma unroll
      for (int r = 0; r < 4; ++r) {
        int i = 16 * wv + 4 * l16 + r, j = 16 * n + l15;
        const float zv = zz[n][r];
        const int base = i * 64 + j;
#pragma unroll
        for (int o = 0; o < 4; ++o)
          po[o] = fmaf(zv, lin_w[o * 4096 + base], po[o]);
      }
#pragma unroll
    for (int o = 0; o < 4; ++o) sm.r.red[tid][o] = po[o];
  }
  __syncthreads();
  if (tid < 64) {
    const int g = tid >> 4, li = tid & 15;
    float s = 0.f;
#pragma unroll
    for (int q = 0; q < 16; ++q) s += sm.r.red[li + 16 * q][g];
#pragma unroll
    for (int d = 8; d >= 1; d >>= 1) s += __shfl_down(s, d);
    if (li == 0) out[b * 4 + g] = s + lin_b[g];
  }
}

extern "C" void kernel_launch(void* const* d_in, const int* in_sizes, int n_in,
                              void* d_out, int out_size, void* d_ws, size_t ws_size,
                              hipStream_t stream) {
  const float* X     = (const float*)d_in[0];
  const float* W     = (const float*)d_in[1];
  const float* lin_w = (const float*)d_in[2];
  const float* lin_b = (const float*)d_in[3];
  float* out = (float*)d_out;
  spdnet_fused11_kernel<<<512, 512, 0, stream>>>(X, W, lin_w, lin_b, out);
}

// Round 14
// 69.147 us; speedup vs baseline: 1.2673x; 1.2673x over previous
//
#include <hip/hip_runtime.h>
#include <math.h>

#define NDEG 12

typedef unsigned short u16;
typedef unsigned int u32;
typedef _Float16 f16;
typedef __attribute__((ext_vector_type(8))) _Float16 f16x8;
typedef __attribute__((ext_vector_type(8))) short bf16x8;
typedef __attribute__((ext_vector_type(4))) float f32x4;

#define MFMA_F16(a, b, c)  __builtin_amdgcn_mfma_f32_16x16x32_f16(a, b, c, 0, 0, 0)
#define MFMA_BF16(a, b, c) __builtin_amdgcn_mfma_f32_16x16x32_bf16(a, b, c, 0, 0, 0)

__device__ __forceinline__ u32 fbits(float x) { return __float_as_uint(x); }
__device__ __forceinline__ float fval(u32 u) { return __uint_as_float(u); }
__device__ __forceinline__ f32x4 zero4() {
  f32x4 z; z[0] = 0.f; z[1] = 0.f; z[2] = 0.f; z[3] = 0.f; return z;
}
__device__ __forceinline__ u16 f16bits(f16 x) { u16 u; __builtin_memcpy(&u, &x, 2); return u; }
__device__ __forceinline__ float f16tof(u16 u) { f16 h; __builtin_memcpy(&h, &u, 2); return (float)h; }

// bf16 hi (trunc) + bf16 lo (RNE remainder) split  [rounds 2-13 known-good]
__device__ __forceinline__ void split2(float x, u32& h, u32& l) {
  u32 u = fbits(x);
  h = u >> 16;
  float lo = x - fval(u & 0xFFFF0000u);
  u32 v = fbits(lo);
  l = (v + 0x7FFFu + ((v >> 16) & 1u)) >> 16;
}
__device__ __forceinline__ void writePair(u32* Hw, u32* Lw, int widx, float v, int lane) {
  float pv = __shfl_xor(v, 1);
  u32 hv, lv, hp, lp;
  split2(v, hv, lv);
  split2(pv, hp, lp);
  const bool even = (lane & 1) == 0;
  u32 word = even ? (hv | (hp << 16)) : (lp | (lv << 16));
  u32* base = even ? Hw : Lw;
  base[widx] = word;
}

struct CovPh { u16 buf[3][8192]; };                      // 3 x 16KB f16 tiles [128][64], swizzled
struct ProjPh { u16 Cov[128][136]; u16 Wt[64][136]; };   // 52224 B
struct ChebPh {
  u16 MH[64][72]; u16 ML[64][72];
  u16 TbH[2][64][72]; u16 TbL[2][64][72];
};                                                        // 55296 B
union SmemU { CovPh a; ProjPh p; ChebPh c; };

// Gram over upper-triangle tiles: wave W owns rows I1=W (tiles (W,J) J=W..7)
// and I2=7-W (tiles (7-W,J) J=7-W..7) -> 9 tiles; +2 xsum MFMAs (frags 2W,2W+1).
template <int W>
__device__ __forceinline__ void gramTiles(const char* bufb, int fo0, int fo1,
                                          f32x4 (&acc)[9], f32x4& xsA, f32x4& xsB,
                                          f16x8 ones) {
  constexpr int I2 = 7 - W;
#pragma unroll
  for (int ch = 0; ch < 2; ++ch) {
    const int fo = ch ? fo1 : fo0;
    f16x8 F[8];
#pragma unroll
    for (int J = W; J < 8; ++J)
      F[J] = *(const f16x8*)(bufb + J * 2048 + fo);
#pragma unroll
    for (int J = W; J < 8; ++J)
      acc[J - W] = MFMA_F16(F[W], F[J], acc[J - W]);
#pragma unroll
    for (int J = I2; J < 8; ++J)
      acc[(8 - W) + (J - I2)] = MFMA_F16(F[I2], F[J], acc[(8 - W) + (J - I2)]);
    xsA = MFMA_F16(F[2 * W], ones, xsA);
    xsB = MFMA_F16(F[2 * W + 1], ones, xsB);
  }
}

__device__ __forceinline__ void covTile(u16* Cov, const f32x4& v, int I, int J,
                                        int l15, int l16, bool mirror) {
#pragma unroll
  for (int r = 0; r < 4; ++r) {
    int row = 16 * I + 4 * l16 + r;
    int col = 16 * J + l15;
    u16 h = f16bits((f16)(v[r] * 1e-3f));
    Cov[row * 136 + col] = h;
    if (mirror) Cov[col * 136 + row] = h;
  }
}

template <int W>
__device__ __forceinline__ void covStore(u16* Cov, const f32x4 (&acc)[9], int l15, int l16) {
  constexpr int I2 = 7 - W;
#pragma unroll
  for (int J = W; J < 8; ++J)
    covTile(Cov, acc[J - W], W, J, l15, l16, J != W);
#pragma unroll
  for (int J = I2; J < 8; ++J)
    covTile(Cov, acc[(8 - W) + (J - I2)], I2, J, l15, l16, J != I2);
}

__global__ __launch_bounds__(256, 2) void spdnet_fused4_kernel(
    const float* __restrict__ X, const float* __restrict__ W,
    const float* __restrict__ lin_w, const float* __restrict__ lin_b,
    float* __restrict__ out)
{
  __shared__ SmemU sm;
  __shared__ float mwL[64];
  __shared__ float xsL[128];
  __shared__ float redL[256][4];

  const int tid = threadIdx.x;
  const int lane = tid & 63;
  const int wv = tid >> 6;
  const int l15 = lane & 15;
  const int l16 = lane >> 4;
  const int b = blockIdx.x;
  const float* __restrict__ Xb = X + (size_t)b * 128000u;

  // ================= phase A: Cov = X X^T, f16 MFMA, symmetric tiles =================
  // load map: instr q covers row 32wv+4q+l16, t = 4*l15 .. (+4) within 64-t tile
  const float* rowp[8];
  int ldsoff[8];
#pragma unroll
  for (int q = 0; q < 8; ++q) {
    const int rq = 32 * wv + 4 * q + l16;
    rowp[q] = Xb + rq * 1000 + 4 * l15;
    ldsoff[q] = rq * 128 + ((8 * l15) ^ ((rq & 7) << 4));   // f16 tile byte addr
  }
  const int swz = (l15 & 7) << 4;
  const int fo0 = l15 * 128 + ((16 * l16) ^ swz);           // frag read, ch 0
  const int fo1 = l15 * 128 + ((16 * l16 + 64) ^ swz);      // frag read, ch 1

  f16x8 ones;
#pragma unroll
  for (int i = 0; i < 8; ++i) ones[i] = (f16)1.0f;

  f32x4 acc[9];
#pragma unroll
  for (int u = 0; u < 9; ++u) acc[u] = zero4();
  f32x4 xsA = zero4(), xsB = zero4();

  char* bufB = (char*)&sm.a.buf[0][0];
  auto bufp = [&](int i) -> char* { return bufB + i * 16384; };

  // two STATICALLY-NAMED register tile buffers (no runtime pointer select -> no scratch)
  float4 ldA[8], ldB[8];
  auto GRAM = [&](const char* bb) {
    switch (wv) {
      case 0: gramTiles<0>(bb, fo0, fo1, acc, xsA, xsB, ones); break;
      case 1: gramTiles<1>(bb, fo0, fo1, acc, xsA, xsB, ones); break;
      case 2: gramTiles<2>(bb, fo0, fo1, acc, xsA, xsB, ones); break;
      default: gramTiles<3>(bb, fo0, fo1, acc, xsA, xsB, ones); break;
    }
  };

#define LOADT(ld, tile)                                           \
  {                                                               \
    _Pragma("unroll")                                             \
    for (int q = 0; q < 8; ++q)                                   \
      ld[q] = *(const float4*)(rowp[q] + (tile) * 64);            \
  }
#define LOADT_TAIL(ld)                                            \
  {                                                               \
    const bool valid = (4 * l15) < 40;                            \
    const int toff = valid ? 960 : (996 - 4 * l15);               \
    _Pragma("unroll")                                             \
    for (int q = 0; q < 8; ++q) {                                 \
      float4 v = *(const float4*)(rowp[q] + toff);                \
      ld[q] = valid ? v : make_float4(0.f, 0.f, 0.f, 0.f);        \
    }                                                             \
  }
#define STAGE(bb, ld)                                             \
  {                                                               \
    char* bp_ = (bb);                                             \
    _Pragma("unroll")                                             \
    for (int q = 0; q < 8; ++q) {                                 \
      u32 w0 = (u32)f16bits((f16)ld[q].x) | ((u32)f16bits((f16)ld[q].y) << 16); \
      u32 w1 = (u32)f16bits((f16)ld[q].z) | ((u32)f16bits((f16)ld[q].w) << 16); \
      uint2 wr; wr.x = w0; wr.y = w1;                             \
      *(uint2*)(bp_ + ldsoff[q]) = wr;                            \
    }                                                             \
  }

  // prologue: tiles 0 (ldA), 1 (ldB) in flight; stage 0
  LOADT(ldA, 0);
  LOADT(ldB, 1);
  asm volatile("s_waitcnt vmcnt(8)" ::: "memory");
  STAGE(bufp(0), ldA);

  // 16 iterations, unrolled x2: even it -> load ldA / stage ldB; odd -> swap
  for (int p = 0; p < 8; ++p) {
    const int it0 = 2 * p;
    const int it1 = it0 + 1;
    // ---- even body ----
    {
      const int nt = it0 + 2;
      if (nt <= 15) {
        if (nt == 15) { LOADT_TAIL(ldA); } else { LOADT(ldA, nt); }
        asm volatile("s_waitcnt vmcnt(8)" ::: "memory");
      } else {
        asm volatile("s_waitcnt vmcnt(0)" ::: "memory");
      }
      STAGE(bufp((it0 + 1) % 3), ldB);   // tile it0+1 (<=15 always)
      asm volatile("s_waitcnt lgkmcnt(0)" ::: "memory");
      __builtin_amdgcn_s_barrier();
      GRAM(bufp(it0 % 3));
    }
    // ---- odd body ----
    {
      const int nt = it1 + 2;
      if (nt <= 15) {
        if (nt == 15) { LOADT_TAIL(ldB); } else { LOADT(ldB, nt); }
        asm volatile("s_waitcnt vmcnt(8)" ::: "memory");
      } else {
        asm volatile("s_waitcnt vmcnt(0)" ::: "memory");
      }
      if (it1 + 1 <= 15) STAGE(bufp((it1 + 1) % 3), ldA);
      asm volatile("s_waitcnt lgkmcnt(0)" ::: "memory");
      __builtin_amdgcn_s_barrier();
      GRAM(bufp(it1 % 3));
    }
  }
#undef LOADT
#undef LOADT_TAIL
#undef STAGE

  // row sums (from xsum MFMAs; cols duplicated -> take l15==0 lanes)
  if (l15 == 0) {
#pragma unroll
    for (int r = 0; r < 4; ++r) {
      xsL[32 * wv + 4 * l16 + r]      = xsA[r];
      xsL[32 * wv + 16 + 4 * l16 + r] = xsB[r];
    }
  }
  __syncthreads();   // phase-A LDS reads done -> overlay allowed

  // ================= phase P: materialize Cov (f16, *1e-3) + Wt =================
  {
    u16* CovP = &sm.p.Cov[0][0];
    switch (wv) {
      case 0: covStore<0>(CovP, acc, l15, l16); break;
      case 1: covStore<1>(CovP, acc, l15, l16); break;
      case 2: covStore<2>(CovP, acc, l15, l16); break;
      default: covStore<3>(CovP, acc, l15, l16); break;
    }
    u16* WtP = &sm.p.Wt[0][0];
    const int c = tid & 127, dh = tid >> 7;
    const float4* wp = (const float4*)(W + c * 64 + 32 * dh);
#pragma unroll
    for (int q = 0; q < 8; ++q) {
      float4 v = wp[q];
      int d0 = 32 * dh + 4 * q;
      WtP[(d0    ) * 136 + c] = f16bits((f16)v.x);
      WtP[(d0 + 1) * 136 + c] = f16bits((f16)v.y);
      WtP[(d0 + 2) * 136 + c] = f16bits((f16)v.z);
      WtP[(d0 + 3) * 136 + c] = f16bits((f16)v.w);
    }
  }
  __syncthreads();

  // mw = W^T xsum * 1e-3 (wave 0; overlaps P MFMA on other waves)
  if (tid < 64) {
    float s = 0.f;
    for (int c = 0; c < 128; ++c)
      s = fmaf(f16tof(sm.p.Wt[tid][c]), xsL[c], s);
    mwL[tid] = s * 1.0e-3f;
  }

  // ---- P = Cov * W  (fp16 MFMA; wave wv owns rows 32wv..32wv+32) ----
  const u16* CovP = &sm.p.Cov[0][0];
  const u16* WtP  = &sm.p.Wt[0][0];
  f32x4 pAcc[2][4];
#pragma unroll
  for (int ti = 0; ti < 2; ++ti)
#pragma unroll
    for (int n = 0; n < 4; ++n) pAcc[ti][n] = zero4();
#pragma unroll
  for (int ch = 0; ch < 4; ++ch) {
    f16x8 aC[2], bw[4];
#pragma unroll
    for (int ti = 0; ti < 2; ++ti)
      aC[ti] = *(const f16x8*)&CovP[(32 * wv + 16 * ti + l15) * 136 + 8 * l16 + 32 * ch];
#pragma unroll
    for (int n = 0; n < 4; ++n)
      bw[n] = *(const f16x8*)&WtP[(16 * n + l15) * 136 + 8 * l16 + 32 * ch];
#pragma unroll
    for (int ti = 0; ti < 2; ++ti)
#pragma unroll
      for (int n = 0; n < 4; ++n)
        pAcc[ti][n] = MFMA_F16(aC[ti], bw[n], pAcc[ti][n]);
  }
  __syncthreads();   // Cov reads done -> Pt may overlay

  // ---- Pt[d][c] = P[c][d]  (fp16, overlays Cov) ----
  {
    u16* PtP = (u16*)&sm.p.Cov[0][0];
#pragma unroll
    for (int ti = 0; ti < 2; ++ti)
#pragma unroll
      for (int n = 0; n < 4; ++n)
#pragma unroll
        for (int r = 0; r < 4; ++r) {
          int c = 32 * wv + 16 * ti + 4 * l16 + r;
          int d = 16 * n + l15;
          PtP[d * 136 + c] = f16bits((f16)pAcc[ti][n][r]);
        }
  }
  __syncthreads();

  // ---- Y = W^T P  (wave wv owns rows 16wv..16wv+16) ----
  const u16* PtP = (const u16*)&sm.p.Cov[0][0];
  f32x4 yAcc[4];
#pragma unroll
  for (int n = 0; n < 4; ++n) yAcc[n] = zero4();
#pragma unroll
  for (int ch = 0; ch < 4; ++ch) {
    f16x8 aW = *(const f16x8*)&WtP[(16 * wv + l15) * 136 + 8 * l16 + 32 * ch];
#pragma unroll
    for (int n = 0; n < 4; ++n) {
      f16x8 bP = *(const f16x8*)&PtP[(16 * n + l15) * 136 + 8 * l16 + 32 * ch];
      yAcc[n] = MFMA_F16(aW, bP, yAcc[n]);
    }
  }
  __syncthreads();   // Wt/Pt dead -> Chebyshev planes may overlay

  // ================= phase C: M init + Chebyshev matrix-log (bf16 3-term) =================
  const float CC = 1.125f;
  const float IH = 1.0f / 0.875f;
  const float uu = 0.875f / 1.125f;
  const float rho = (sqrtf(1.0f - uu * uu) - 1.0f) / uu;   // ~ -0.47759
  const float a0c = logf(CC / (1.0f + rho * rho));
  const float a1c = -2.0f * rho;

  f32x4 zz[4], tp[4], tcu[4];
  {
    u32* MHw = (u32*)&sm.c.MH[0][0];
    u32* MLw = (u32*)&sm.c.ML[0][0];
#pragma unroll
    for (int n = 0; n < 4; ++n)
#pragma unroll
      for (int r = 0; r < 4; ++r) {
        int i = 16 * wv + 4 * l16 + r, j = 16 * n + l15;
        float y = yAcc[n][r] - mwL[i] * mwL[j];
        float m = (y - ((i == j) ? CC : 0.f)) * IH;
        float e = (i == j) ? 1.f : 0.f;
        tp[n][r] = e;
        tcu[n][r] = m;
        zz[n][r] = a0c * e + a1c * m;
        writePair(MHw, MLw, i * 36 + (j >> 1), m, lane);
      }
  }
  __syncthreads();

  bf16x8 aMh[2], aMl[2];
#pragma unroll
  for (int ch = 0; ch < 2; ++ch) {
    aMh[ch] = *(const bf16x8*)&sm.c.MH[16 * wv + l15][8 * l16 + 32 * ch];
    aMl[ch] = *(const bf16x8*)&sm.c.ML[16 * wv + l15][8 * l16 + 32 * ch];
  }

  float rhok = rho;
  for (int k = 2; k <= NDEG; ++k) {
    const u16 (*srcH)[72] = (k == 2) ? sm.c.MH : sm.c.TbH[(k - 1) & 1];
    const u16 (*srcL)[72] = (k == 2) ? sm.c.ML : sm.c.TbL[(k - 1) & 1];
    f32x4 p[4];
#pragma unroll
    for (int n = 0; n < 4; ++n) p[n] = zero4();
#pragma unroll
    for (int ch = 0; ch < 2; ++ch) {
#pragma unroll
      for (int n = 0; n < 4; ++n) {
        bf16x8 bh = *(const bf16x8*)&srcH[16 * n + l15][8 * l16 + 32 * ch];
        bf16x8 bl = *(const bf16x8*)&srcL[16 * n + l15][8 * l16 + 32 * ch];
        p[n] = MFMA_BF16(aMh[ch], bh, p[n]);
        p[n] = MFMA_BF16(aMh[ch], bl, p[n]);
        p[n] = MFMA_BF16(aMl[ch], bh, p[n]);
      }
    }
    rhok *= rho;
    const float ak = (-2.0f / (float)k) * rhok;
    u32* dH = (u32*)&sm.c.TbH[k & 1][0][0];
    u32* dL = (u32*)&sm.c.TbL[k & 1][0][0];
#pragma unroll
    for (int n = 0; n < 4; ++n) {
      f32x4 tn;
#pragma unroll
      for (int r = 0; r < 4; ++r) {
        tn[r] = 2.f * p[n][r] - tp[n][r];
        zz[n][r] = fmaf(ak, tn[r], zz[n][r]);
      }
      tp[n] = tcu[n];
      tcu[n] = tn;
      if (k < NDEG) {
#pragma unroll
        for (int r = 0; r < 4; ++r) {
          int row = 16 * wv + 4 * l16 + r, col = 16 * n + l15;
          writePair(dH, dL, row * 36 + (col >> 1), tn[r], lane);
        }
      }
    }
    if (k < NDEG) __syncthreads();
  }

  // ================= classifier =================
  float po[4] = {0.f, 0.f, 0.f, 0.f};
#pragma unroll
  for (int n = 0; n < 4; ++n)
#pragma unroll
    for (int r = 0; r < 4; ++r) {
      int i = 16 * wv + 4 * l16 + r, j = 16 * n + l15;
      const float zv = zz[n][r];
      const int base = i * 64 + j;
#pragma unroll
      for (int o = 0; o < 4; ++o)
        po[o] = fmaf(zv, lin_w[o * 4096 + base], po[o]);
    }
#pragma unroll
  for (int o = 0; o < 4; ++o) redL[tid][o] = po[o];
  __syncthreads();
  if (tid < 64) {
    const int g = tid >> 4, li = tid & 15;
    float s = 0.f;
#pragma unroll
    for (int q = 0; q < 16; ++q) s += redL[li + 16 * q][g];
#pragma unroll
    for (int d = 8; d >= 1; d >>= 1) s += __shfl_down(s, d);
    if (li == 0) out[b * 4 + g] = s + lin_b[g];
  }
}

extern "C" void kernel_launch(void* const* d_in, const int* in_sizes, int n_in,
                              void* d_out, int out_size, void* d_ws, size_t ws_size,
                              hipStream_t stream) {
  const float* X     = (const float*)d_in[0];
  const float* W     = (const float*)d_in[1];
  const float* lin_w = (const float*)d_in[2];
  const float* lin_b = (const float*)d_in[3];
  float* out = (float*)d_out;
  spdnet_fused4_kernel<<<512, 256, 0, stream>>>(X, W, lin_w, lin_b, out);
}